// Round 1
// baseline (37.641 us; speedup 1.0000x reference)
//
#include <hip/hip_runtime.h>
#include <hip/hip_bf16.h>

// Problem constants (from reference)
#define NN      6400   // total nodes
#define NG      200    // nodes per graph
#define NB      32     // graphs (NN/NG)
#define FIN     128
#define FOUT    128

// ---------------------------------------------------------------------------
// Kernel 1: support = feat @ weight   ([6400,128] @ [128,128] -> [6400,128])
// One block per 32 rows; W + feat tile staged in LDS; 4x4 micro-tile/thread.
// ---------------------------------------------------------------------------
#define K1_ROWS 32

__global__ __launch_bounds__(256) void support_kernel(
    const float* __restrict__ feat,
    const float* __restrict__ weight,
    float* __restrict__ support)
{
    __shared__ float sW[FIN][FOUT];     // 64 KB
    __shared__ float sF[K1_ROWS][FIN];  // 16 KB

    const int t    = threadIdx.x;
    const int row0 = blockIdx.x * K1_ROWS;

    // Stage W: 16384 floats = 4096 float4; 16 per thread.
    const float4* W4  = (const float4*)weight;
    float4*       sW4 = (float4*)&sW[0][0];
#pragma unroll
    for (int i = 0; i < 16; ++i) sW4[t + i * 256] = W4[t + i * 256];

    // Stage feat tile: 32*128 floats = 1024 float4; 4 per thread.
    const float4* F4  = (const float4*)(feat + (size_t)row0 * FIN);
    float4*       sF4 = (float4*)&sF[0][0];
#pragma unroll
    for (int i = 0; i < 4; ++i) sF4[t + i * 256] = F4[t + i * 256];

    __syncthreads();

    // thread -> rows r0..r0+3, cols c0..c0+3
    const int r0 = (t >> 5) * 4;   // 8 row groups * 4 rows = 32 rows
    const int c0 = (t & 31) * 4;   // 32 col groups * 4 cols = 128 cols

    float acc[4][4] = {};
#pragma unroll 4
    for (int k = 0; k < FIN; ++k) {
        const float4 w = *(const float4*)&sW[k][c0];
#pragma unroll
        for (int i = 0; i < 4; ++i) {
            const float f = sF[r0 + i][k];
            acc[i][0] += f * w.x;
            acc[i][1] += f * w.y;
            acc[i][2] += f * w.z;
            acc[i][3] += f * w.w;
        }
    }

#pragma unroll
    for (int i = 0; i < 4; ++i) {
        *(float4*)&support[(size_t)(row0 + r0 + i) * FOUT + c0] =
            make_float4(acc[i][0], acc[i][1], acc[i][2], acc[i][3]);
    }
}

// ---------------------------------------------------------------------------
// Kernel 2: out[b] = (sigmoid(adj_block_b) * mask) @ support_b
// mask = 0.5*(R + R^T) + I, shared across graphs.
// One block per (graph, 40-row slab): 32*5 = 160 blocks.
// ---------------------------------------------------------------------------
#define K2_ROWS 40

__global__ __launch_bounds__(256) void bmm_kernel(
    const float* __restrict__ adj,
    const float* __restrict__ rew,
    const float* __restrict__ support,
    float* __restrict__ out)
{
    const int b    = blockIdx.x / 5;     // graph index
    const int slab = blockIdx.x % 5;     // which 40-row slab
    const int i0   = slab * K2_ROWS;     // local row offset within graph
    const int t    = threadIdx.x;

    __shared__ float sM[K2_ROWS][NG];    // 40*200*4 = 32 KB

    // Build masked matrix rows [i0, i0+40) x [0, 200)
    for (int idx = t; idx < K2_ROWS * NG; idx += 256) {
        const int i  = idx / NG;
        const int j  = idx % NG;
        const int gi = i0 + i;           // local row in graph [0,200)
        const float a = adj[(size_t)(b * NG + gi) * NN + (size_t)b * NG + j];
        const float s = 1.0f / (1.0f + __expf(-a));
        const float m = 0.5f * (rew[gi * NG + j] + rew[j * NG + gi]) +
                        (gi == j ? 1.0f : 0.0f);
        sM[i][j] = s * m;
    }
    __syncthreads();

    // Each thread: 5 rows x 4 cols of the [40 x 128] output slab.
    const int r0 = (t >> 5) * 5;   // 8 row groups * 5 rows = 40
    const int c0 = (t & 31) * 4;   // 32 col groups * 4 cols = 128

    const float* __restrict__ S = support + (size_t)b * NG * FOUT;

    float acc[5][4] = {};
    for (int j = 0; j < NG; ++j) {
        const float4 s = *(const float4*)&S[(size_t)j * FOUT + c0];
#pragma unroll
        for (int i = 0; i < 5; ++i) {
            const float m = sM[r0 + i][j];
            acc[i][0] += m * s.x;
            acc[i][1] += m * s.y;
            acc[i][2] += m * s.z;
            acc[i][3] += m * s.w;
        }
    }

#pragma unroll
    for (int i = 0; i < 5; ++i) {
        *(float4*)&out[(size_t)(b * NG + i0 + r0 + i) * FOUT + c0] =
            make_float4(acc[i][0], acc[i][1], acc[i][2], acc[i][3]);
    }
}

// ---------------------------------------------------------------------------
extern "C" void kernel_launch(void* const* d_in, const int* in_sizes, int n_in,
                              void* d_out, int out_size, void* d_ws, size_t ws_size,
                              hipStream_t stream)
{
    const float* adj    = (const float*)d_in[0];  // [6400, 6400]
    const float* feat   = (const float*)d_in[1];  // [6400, 128]
    const float* weight = (const float*)d_in[2];  // [128, 128]
    const float* rew    = (const float*)d_in[3];  // [200, 200]
    float*       out    = (float*)d_out;          // [6400, 128]
    float*       support = (float*)d_ws;          // [6400, 128] scratch (3.28 MB)

    // Kernel 1: support = feat @ weight
    support_kernel<<<NN / K1_ROWS, 256, 0, stream>>>(feat, weight, support);

    // Kernel 2: per-graph masked bmm
    bmm_kernel<<<NB * (NG / K2_ROWS), 256, 0, stream>>>(adj, rew, support, out);
}